// Round 1
// baseline (2799.113 us; speedup 1.0000x reference)
//
#include <hip/hip_runtime.h>
#include <hip/hip_bf16.h>

// EMD via Sinkhorn (EPS=0.02, 50 iters), B=16, N=M=2048, 3-D points.
// All potentials kept in base-2 log domain scaled by 1/EPS:
//   u2 = (f/EPS)*log2(e), v2 = (g/EPS)*log2(e)
// Half-iteration: u2[n] = -log2(N) - LSE2_m( v2[m] - d(n,m)*KSCALE )
// Loss: (1/B) * sum_{b,n,m} 2^(u2[n]+v2[m]-d*KSCALE) * d

#define BATCH 16
#define NPTS 2048
#define TPR 8            // threads per row
#define RPB 32           // rows per block (256/TPR)
#define BLOCKS_PER_BATCH 64
#define KSCALE 72.13475204444817f   // (1/0.02) * log2(e)
#define NEG_LOG2N (-11.0f)          // -log2(2048)

#if __has_builtin(__builtin_amdgcn_exp2f)
#define EX2(x) __builtin_amdgcn_exp2f(x)
#else
#define EX2(x) exp2f(x)
#endif
#if __has_builtin(__builtin_amdgcn_logf)
#define LG2(x) __builtin_amdgcn_logf(x)
#else
#define LG2(x) log2f(x)
#endif
#if __has_builtin(__builtin_amdgcn_sqrtf)
#define SQRTF(x) __builtin_amdgcn_sqrtf(x)
#else
#define SQRTF(x) sqrtf(x)
#endif

__global__ __launch_bounds__(256) void prep_kernel(
    const float* __restrict__ tpl, const float* __restrict__ src,
    float4* __restrict__ Xp, float4* __restrict__ Yp, float* __restrict__ v2) {
  int i = blockIdx.x * 256 + threadIdx.x;
  if (i < BATCH * NPTS) {
    float x0 = tpl[3*i], x1 = tpl[3*i+1], x2 = tpl[3*i+2];
    Xp[i] = make_float4(x0, x1, x2, x0*x0 + x1*x1 + x2*x2);
    float y0 = src[3*i], y1 = src[3*i+1], y2 = src[3*i+2];
    Yp[i] = make_float4(y0, y1, y2, y0*y0 + y1*y1 + y2*y2);
    v2[i] = 0.0f;
  }
}

// One Sinkhorn half-step: for 32 rows of batch b, compute
//   wout[n] = -log2(N) - LSE2_m( win[m] - d(n,m)*KSCALE )
// Fully symmetric: call with (Xp,Yp,v2,u2) for f-update, (Yp,Xp,u2,v2) for g-update.
__global__ __launch_bounds__(256, 4) void sink_half(
    const float4* __restrict__ Rp,   // points whose potentials we update
    const float4* __restrict__ Cp,   // points scanned (columns)
    const float* __restrict__ win,   // incoming potential (base-2, scaled)
    float* __restrict__ wout) {
  __shared__ float4 sY[NPTS];   // 32 KB
  __shared__ float  sv[NPTS];   // 8 KB
  int bx = blockIdx.x;
  int b = bx >> 6;              // 64 row-blocks per batch
  int rblk = bx & 63;
  int tid = threadIdx.x;
  const float4* cb = Cp + b * NPTS;
  const float*  vb = win + b * NPTS;
  for (int i = tid; i < NPTS; i += 256) { sY[i] = cb[i]; sv[i] = vb[i]; }
  __syncthreads();

  int row = tid >> 3, slice = tid & 7;
  int n = rblk * RPB + row;
  float4 xp = Rp[b * NPTS + n];

  float runm = -1e30f, runs = 0.0f;
  for (int J = 0; J < NPTS / (TPR * 4); ++J) {   // 64 chunk-iterations
    float t[4];
#pragma unroll
    for (int k = 0; k < 4; ++k) {
      int m = J * 32 + k * 8 + slice;           // 8 consecutive m per k across slices
      float4 yp = sY[m];
      float vm = sv[m];
      float dot = fmaf(xp.z, yp.z, fmaf(xp.y, yp.y, xp.x * yp.x));
      float sq  = fmaf(-2.0f, dot, xp.w + yp.w);
      float d   = SQRTF(fmaxf(sq, 1e-12f));
      t[k] = fmaf(d, -KSCALE, vm);
    }
    float tm = fmaxf(fmaxf(t[0], t[1]), fmaxf(t[2], t[3]));
    float nm = fmaxf(runm, tm);
    float ssum = EX2(t[0] - nm) + EX2(t[1] - nm) + EX2(t[2] - nm) + EX2(t[3] - nm);
    runs = fmaf(runs, EX2(runm - nm), ssum);
    runm = nm;
  }

  // combine the 8 slices of this row (adjacent lanes)
#pragma unroll
  for (int off = 1; off < TPR; off <<= 1) {
    float om = __shfl_xor(runm, off);
    float os = __shfl_xor(runs, off);
    float nm = fmaxf(runm, om);
    runs = fmaf(runs, EX2(runm - nm), os * EX2(om - nm));
    runm = nm;
  }
  if (slice == 0)
    wout[b * NPTS + n] = NEG_LOG2N - (runm + LG2(runs));
}

// Final pass: partial[block] = sum over this block's 32 rows of sum_m 2^(u2+v2-d*K)*d
__global__ __launch_bounds__(256, 4) void final_kernel(
    const float4* __restrict__ Xp, const float4* __restrict__ Yp,
    const float* __restrict__ u2, const float* __restrict__ v2,
    float* __restrict__ partials) {
  __shared__ float4 sY[NPTS];
  __shared__ float  sv[NPTS];
  __shared__ float  red[4];
  int bx = blockIdx.x;
  int b = bx >> 6;
  int rblk = bx & 63;
  int tid = threadIdx.x;
  const float4* cb = Yp + b * NPTS;
  const float*  vb = v2 + b * NPTS;
  for (int i = tid; i < NPTS; i += 256) { sY[i] = cb[i]; sv[i] = vb[i]; }
  __syncthreads();

  int row = tid >> 3, slice = tid & 7;
  int n = rblk * RPB + row;
  float4 xp = Xp[b * NPTS + n];
  float un = u2[b * NPTS + n];

  float acc = 0.0f;
  for (int J = 0; J < NPTS / (TPR * 4); ++J) {
#pragma unroll
    for (int k = 0; k < 4; ++k) {
      int m = J * 32 + k * 8 + slice;
      float4 yp = sY[m];
      float vm = sv[m];
      float dot = fmaf(xp.z, yp.z, fmaf(xp.y, yp.y, xp.x * yp.x));
      float sq  = fmaf(-2.0f, dot, xp.w + yp.w);
      float d   = SQRTF(fmaxf(sq, 1e-12f));
      float e   = EX2(fmaf(d, -KSCALE, un + vm));
      acc = fmaf(e, d, acc);
    }
  }
  // wave reduce then block reduce (deterministic)
#pragma unroll
  for (int off = 1; off < 64; off <<= 1) acc += __shfl_xor(acc, off);
  if ((tid & 63) == 0) red[tid >> 6] = acc;
  __syncthreads();
  if (tid == 0) partials[bx] = (red[0] + red[1]) + (red[2] + red[3]);
}

__global__ __launch_bounds__(256) void reduce_kernel(
    const float* __restrict__ partials, float* __restrict__ out) {
  __shared__ float red[4];
  int tid = threadIdx.x;
  float a = (partials[tid] + partials[tid + 256]) +
            (partials[tid + 512] + partials[tid + 768]);
#pragma unroll
  for (int off = 1; off < 64; off <<= 1) a += __shfl_xor(a, off);
  if ((tid & 63) == 0) red[tid >> 6] = a;
  __syncthreads();
  if (tid == 0) out[0] = ((red[0] + red[1]) + (red[2] + red[3])) * (1.0f / BATCH);
}

extern "C" void kernel_launch(void* const* d_in, const int* in_sizes, int n_in,
                              void* d_out, int out_size, void* d_ws, size_t ws_size,
                              hipStream_t stream) {
  const float* tpl = (const float*)d_in[0];
  const float* src = (const float*)d_in[1];
  float* out = (float*)d_out;
  char* ws = (char*)d_ws;

  const size_t ptsBytes = (size_t)BATCH * NPTS * sizeof(float4);   // 512 KB
  const size_t potBytes = (size_t)BATCH * NPTS * sizeof(float);    // 128 KB
  float4* Xp = (float4*)ws;
  float4* Yp = (float4*)(ws + ptsBytes);
  float*  u2 = (float*)(ws + 2 * ptsBytes);
  float*  v2 = (float*)(ws + 2 * ptsBytes + potBytes);
  float*  partials = (float*)(ws + 2 * ptsBytes + 2 * potBytes);   // 4 KB

  const int nblk = BATCH * BLOCKS_PER_BATCH;   // 1024

  prep_kernel<<<(BATCH * NPTS + 255) / 256, 256, 0, stream>>>(tpl, src, Xp, Yp, v2);
  for (int it = 0; it < 50; ++it) {
    sink_half<<<nblk, 256, 0, stream>>>(Xp, Yp, v2, u2);   // f-update
    sink_half<<<nblk, 256, 0, stream>>>(Yp, Xp, u2, v2);   // g-update
  }
  final_kernel<<<nblk, 256, 0, stream>>>(Xp, Yp, u2, v2, partials);
  reduce_kernel<<<1, 256, 0, stream>>>(partials, out);
}